// Round 7
// baseline (57.828 us; speedup 1.0000x reference)
//
#include <hip/hip_runtime.h>

// ESRNN Holt-Winters, B=65536 series, T=512, period M=12.
// One wave (64 threads) per block, one thread per series, 96-step chunks
// (96 % 12 == 0 -> compile-time seasonal ring indices).
// R7 change vs R6: TC 48 -> 96. Doubles the contiguous run length per series
// row per chunk (192B -> 384B) on both the read and write streams — attacks
// DRAM row-buffer locality, which the R6 counters indicate is the limiter
// (stalls consistent with 4.4/6.3 TB/s delivered BW; MLP and DS pipe ruled
// out by arithmetic). Depth-1 prefetch with register reuse (24 f32x4).
// LDS: x-buf 24 KB + o-buf 24 KB = 48 KB -> 3 blocks/CU.

constexpr int TT     = 512;     // timesteps
constexpr int TC     = 96;      // chunk steps
constexpr int NCH    = 5;       // full chunks (480 steps)
constexpr int SW     = 64;      // series per block (one wave)
constexpr int F4C    = TC / 4;  // f4 per series per chunk (24)
constexpr int SROW   = 96;      // LDS row stride in floats (24 slots of 16B)
constexpr int PITCH4 = TT / 4;  // global row pitch in float4 units (128)

typedef float f32x4 __attribute__((ext_vector_type(4)));

#define CBAR() asm volatile("" ::: "memory")   // compiler-only barrier

#define STEPM(XV, SH, SN, OV)                                              \
    do {                                                                   \
        const float s_h_ = ring[SH];                                       \
        const float q_   = (XV) * __builtin_amdgcn_rcpf(s_h_);             \
        const float lb_  = fmaf(b, phi, l);                                \
        const float ln_  = fmaf(alpha, q_, omal * lb_);                    \
        const float bphi_ = b * phi;                                       \
        const float bn_  = fmaf(beta, ln_ - l, ombe * bphi_);              \
        const float lb2_ = fmaf(bn_, phi, ln_);                            \
        const float sn_  = fmaf(gamma, (XV) * __builtin_amdgcn_rcpf(lb2_), \
                                omg * s_h_);                               \
        (OV) = lb2_ * ring[SN];                                            \
        ring[SH] = sn_;                                                    \
        l = ln_; b = bn_;                                                  \
    } while (0)

__global__ __launch_bounds__(64) void esrnn_kernel(
    const float* __restrict__ x,
    const float* __restrict__ p_alpha,
    const float* __restrict__ p_beta,
    const float* __restrict__ p_phi,
    const float* __restrict__ p_gamma,
    const float* __restrict__ l0,
    const float* __restrict__ b0,
    const float* __restrict__ s0,
    float* __restrict__ out)
{
    const int tid = threadIdx.x;
    const int t7  = tid & 7;
    const int series0 = blockIdx.x * SW;
    const int i = series0 + tid;

    __shared__ __align__(16) float lds_x[SW * SROW];   // 24 KB
    __shared__ __align__(16) float lds_o[SW * SROW];   // 24 KB

    const float alpha = p_alpha[0];
    const float beta  = p_beta[0];
    const float phi   = p_phi[0];
    const float gamma = p_gamma[0];
    const float omal  = 1.0f - alpha;
    const float ombe  = 1.0f - beta;
    const float omg   = 1.0f - gamma;

    float l = l0[i];
    float b = b0[i];

    float ring[12];
    {
        const f32x4* s04 = reinterpret_cast<const f32x4*>(s0 + (size_t)i * 12);
        f32x4 sa = s04[0], sb = s04[1], sc = s04[2];
        ring[0] = sa.x; ring[1] = sa.y; ring[2]  = sa.z; ring[3]  = sa.w;
        ring[4] = sb.x; ring[5] = sb.y; ring[6]  = sb.z; ring[7]  = sb.w;
        ring[8] = sc.x; ring[9] = sc.y; ring[10] = sc.z; ring[11] = sc.w;
    }

    // main-chunk tile mapping: flat f4 index f = tid + 64*m over a 64x24 f4
    // tile -> series row r = f/24, time f4-col q = f%24.
    //  gx[m] = global f4 index of (r, q) at chunk 0; +24 per chunk.
    //  lo[m] = swizzled LDS float offset: r*SROW + ((q ^ (r&7)) << 2).
    //          (q = 8a+b; b^e stays in the same octet, so swizzled q < 24.)
    int gx[24], lo[24];
    #pragma unroll
    for (int m = 0; m < 24; ++m) {
        const int f = tid + SW * m;
        const int r = f / 24;
        const int q = f - 24 * r;
        gx[m] = r * PITCH4 + q;
        lo[m] = r * SROW + ((q ^ (r & 7)) << 2);
    }

    const f32x4* x4 = reinterpret_cast<const f32x4*>(x) + (size_t)series0 * PITCH4;
    f32x4*       o4 = reinterpret_cast<f32x4*>(out)     + (size_t)series0 * PITCH4;

    f32x4 vx[24];

    // prologue: load chunk 0
    #pragma unroll
    for (int m = 0; m < 24; ++m)
        vx[m] = x4[gx[m]];

    #pragma unroll 1
    for (int k = 0; k < NCH; ++k) {
        // 1. stage chunk k into LDS, 24 x ds_write_b128 (counted vmcnt on vx)
        #pragma unroll
        for (int m = 0; m < 24; ++m)
            *reinterpret_cast<f32x4*>(&lds_x[lo[m]]) = vx[m];
        CBAR();

        // 2. reuse vx: issue next chunk's loads (cover = compute, ~3K cyc)
        if (k < NCH - 1) {
            #pragma unroll
            for (int m = 0; m < 24; ++m)
                vx[m] = x4[gx[m] + (k + 1) * F4C];
        } else {
            // tail x: 64x8 f4 tile -> r = f>>3, q = f&7
            #pragma unroll
            for (int m = 0; m < 8; ++m) {
                const int f = tid + SW * m;
                vx[m] = x4[(size_t)(f >> 3) * PITCH4 + 120 + (f & 7)];
            }
        }
        CBAR();

        // 3. compute 96 steps: 24 x (b128 read, 4 steps, b128 write);
        //    ring phase is 0 at every chunk start (96 % 12 == 0)
        #pragma unroll
        for (int q = 0; q < 24; ++q) {
            const int sl = tid * SROW + ((q ^ t7) << 2);
            const f32x4 xq = *reinterpret_cast<const f32x4*>(&lds_x[sl]);
            f32x4 oq;
            STEPM(xq.x, (4 * q + 0) % 12, (4 * q + 1) % 12, oq.x);
            STEPM(xq.y, (4 * q + 1) % 12, (4 * q + 2) % 12, oq.y);
            STEPM(xq.z, (4 * q + 2) % 12, (4 * q + 3) % 12, oq.z);
            STEPM(xq.w, (4 * q + 3) % 12, (4 * q + 4) % 12, oq.w);
            *reinterpret_cast<f32x4*>(&lds_o[sl]) = oq;
        }
        CBAR();

        // 4. transpose-read outputs (24 x b128) and non-temporal store
        #pragma unroll
        for (int m = 0; m < 24; ++m) {
            const f32x4 o = *reinterpret_cast<const f32x4*>(&lds_o[lo[m]]);
            __builtin_nontemporal_store(o, &o4[gx[m] + k * F4C]);
        }
        CBAR();
    }

    // ---- tail: steps 480..511 (32 steps, phase 480%12 == 0) ----
    // tail x values were loaded during iteration k == NCH-1 into vx[0..7]
    {
        #pragma unroll
        for (int m = 0; m < 8; ++m) {
            const int f = tid + SW * m;
            const int rt = f >> 3, qt = f & 7;
            lds_x[rt * SROW + ((qt ^ (rt & 7)) << 2) + 0] = vx[m].x;
            *reinterpret_cast<f32x4*>(&lds_x[rt * SROW + ((qt ^ (rt & 7)) << 2)]) = vx[m];
        }
        CBAR();
        #pragma unroll
        for (int q = 0; q < 8; ++q) {
            const int sl = tid * SROW + ((q ^ t7) << 2);
            const f32x4 xq = *reinterpret_cast<const f32x4*>(&lds_x[sl]);
            f32x4 oq;
            STEPM(xq.x, (4 * q + 0) % 12, (4 * q + 1) % 12, oq.x);
            STEPM(xq.y, (4 * q + 1) % 12, (4 * q + 2) % 12, oq.y);
            STEPM(xq.z, (4 * q + 2) % 12, (4 * q + 3) % 12, oq.z);
            STEPM(xq.w, (4 * q + 3) % 12, (4 * q + 4) % 12, oq.w);
            *reinterpret_cast<f32x4*>(&lds_o[sl]) = oq;
        }
        CBAR();
        #pragma unroll
        for (int m = 0; m < 8; ++m) {
            const int f = tid + SW * m;
            const int rt = f >> 3, qt = f & 7;
            const f32x4 o = *reinterpret_cast<const f32x4*>(
                &lds_o[rt * SROW + ((qt ^ (rt & 7)) << 2)]);
            __builtin_nontemporal_store(o, &o4[(size_t)rt * PITCH4 + 120 + qt]);
        }
    }
}

extern "C" void kernel_launch(void* const* d_in, const int* in_sizes, int n_in,
                              void* d_out, int out_size, void* d_ws, size_t ws_size,
                              hipStream_t stream)
{
    const float* x       = (const float*)d_in[0];
    const float* p_alpha = (const float*)d_in[1];
    const float* p_beta  = (const float*)d_in[2];
    const float* p_phi   = (const float*)d_in[3];
    const float* p_gamma = (const float*)d_in[4];
    const float* l0      = (const float*)d_in[5];
    const float* b0      = (const float*)d_in[6];
    const float* s0      = (const float*)d_in[7];
    float* out = (float*)d_out;

    const int B = in_sizes[5];          // l0 has B elements
    const int grid = B / SW;            // 1024 blocks of 64 threads

    esrnn_kernel<<<grid, SW, 0, stream>>>(x, p_alpha, p_beta, p_phi, p_gamma,
                                          l0, b0, s0, out);
}

// Round 8
// 47.822 us; speedup vs baseline: 1.2092x; 1.2092x over previous
//
#include <hip/hip_runtime.h>

// ESRNN Holt-Winters, B=65536 series, T=512, period M=12.
// One wave (64 threads) per block, one thread per series, 96-step chunks
// (96 % 12 == 0 -> compile-time seasonal ring indices).
// R8 = R7's TC=96 retested at FULL occupancy: single in-place LDS buffer
// (24 KB -> 6 blocks/CU; grid needs 4/CU). Compute reads x from lds[sl] and
// writes the output back to the same slot (same-wave in-order DS pipe +
// counted waits make in-place safe); out-phase transpose reads follow, then
// next chunk's staging. Depth-1 prefetch with register reuse (24 f32x4).

constexpr int TT     = 512;     // timesteps
constexpr int TC     = 96;      // chunk steps
constexpr int NCH    = 5;       // full chunks (480 steps)
constexpr int SW     = 64;      // series per block (one wave)
constexpr int F4C    = TC / 4;  // f4 per series per chunk (24)
constexpr int SROW   = 96;      // LDS row stride in floats (24 slots of 16B)
constexpr int PITCH4 = TT / 4;  // global row pitch in float4 units (128)

typedef float f32x4 __attribute__((ext_vector_type(4)));

#define CBAR() asm volatile("" ::: "memory")   // compiler-only barrier

#define STEPM(XV, SH, SN, OV)                                              \
    do {                                                                   \
        const float s_h_ = ring[SH];                                       \
        const float q_   = (XV) * __builtin_amdgcn_rcpf(s_h_);             \
        const float lb_  = fmaf(b, phi, l);                                \
        const float ln_  = fmaf(alpha, q_, omal * lb_);                    \
        const float bphi_ = b * phi;                                       \
        const float bn_  = fmaf(beta, ln_ - l, ombe * bphi_);              \
        const float lb2_ = fmaf(bn_, phi, ln_);                            \
        const float sn_  = fmaf(gamma, (XV) * __builtin_amdgcn_rcpf(lb2_), \
                                omg * s_h_);                               \
        (OV) = lb2_ * ring[SN];                                            \
        ring[SH] = sn_;                                                    \
        l = ln_; b = bn_;                                                  \
    } while (0)

__global__ __launch_bounds__(64) void esrnn_kernel(
    const float* __restrict__ x,
    const float* __restrict__ p_alpha,
    const float* __restrict__ p_beta,
    const float* __restrict__ p_phi,
    const float* __restrict__ p_gamma,
    const float* __restrict__ l0,
    const float* __restrict__ b0,
    const float* __restrict__ s0,
    float* __restrict__ out)
{
    const int tid = threadIdx.x;
    const int t7  = tid & 7;
    const int series0 = blockIdx.x * SW;
    const int i = series0 + tid;

    __shared__ __align__(16) float lds[SW * SROW];   // 24 KB, in-place x/out

    const float alpha = p_alpha[0];
    const float beta  = p_beta[0];
    const float phi   = p_phi[0];
    const float gamma = p_gamma[0];
    const float omal  = 1.0f - alpha;
    const float ombe  = 1.0f - beta;
    const float omg   = 1.0f - gamma;

    float l = l0[i];
    float b = b0[i];

    float ring[12];
    {
        const f32x4* s04 = reinterpret_cast<const f32x4*>(s0 + (size_t)i * 12);
        f32x4 sa = s04[0], sb = s04[1], sc = s04[2];
        ring[0] = sa.x; ring[1] = sa.y; ring[2]  = sa.z; ring[3]  = sa.w;
        ring[4] = sb.x; ring[5] = sb.y; ring[6]  = sb.z; ring[7]  = sb.w;
        ring[8] = sc.x; ring[9] = sc.y; ring[10] = sc.z; ring[11] = sc.w;
    }

    // main-chunk tile mapping: flat f4 index f = tid + 64*m over a 64x24 f4
    // tile -> series row r = f/24, time f4-col q = f%24.
    //  gx[m] = global f4 index of (r, q) at chunk 0; +24 per chunk.
    //  lo[m] = swizzled LDS float offset: r*SROW + ((q ^ (r&7)) << 2)
    //          (q = 8a+b; b^e stays within the octet, so swizzled q < 24).
    int gx[24], lo[24];
    #pragma unroll
    for (int m = 0; m < 24; ++m) {
        const int f = tid + SW * m;
        const int r = f / 24;
        const int q = f - 24 * r;
        gx[m] = r * PITCH4 + q;
        lo[m] = r * SROW + ((q ^ (r & 7)) << 2);
    }

    const f32x4* x4 = reinterpret_cast<const f32x4*>(x) + (size_t)series0 * PITCH4;
    f32x4*       o4 = reinterpret_cast<f32x4*>(out)     + (size_t)series0 * PITCH4;

    f32x4 vx[24];

    // prologue: load chunk 0
    #pragma unroll
    for (int m = 0; m < 24; ++m)
        vx[m] = x4[gx[m]];

    #pragma unroll 1
    for (int k = 0; k < NCH; ++k) {
        // 1. stage chunk k into LDS, 24 x ds_write_b128 (counted vmcnt on vx)
        #pragma unroll
        for (int m = 0; m < 24; ++m)
            *reinterpret_cast<f32x4*>(&lds[lo[m]]) = vx[m];
        CBAR();

        // 2. reuse vx: issue next chunk's loads (covered by ~6K cyc compute)
        if (k < NCH - 1) {
            #pragma unroll
            for (int m = 0; m < 24; ++m)
                vx[m] = x4[gx[m] + (k + 1) * F4C];
        } else {
            // tail x: 64x8 f4 tile -> r = f>>3, q = f&7
            #pragma unroll
            for (int m = 0; m < 8; ++m) {
                const int f = tid + SW * m;
                vx[m] = x4[(size_t)(f >> 3) * PITCH4 + 120 + (f & 7)];
            }
        }
        CBAR();

        // 3. compute 96 steps in place: 24 x (b128 read, 4 steps, b128 write
        //    back to the same slot). Ring phase is 0 at chunk start.
        #pragma unroll
        for (int q = 0; q < 24; ++q) {
            const int sl = tid * SROW + ((q ^ t7) << 2);
            const f32x4 xq = *reinterpret_cast<const f32x4*>(&lds[sl]);
            f32x4 oq;
            STEPM(xq.x, (4 * q + 0) % 12, (4 * q + 1) % 12, oq.x);
            STEPM(xq.y, (4 * q + 1) % 12, (4 * q + 2) % 12, oq.y);
            STEPM(xq.z, (4 * q + 2) % 12, (4 * q + 3) % 12, oq.z);
            STEPM(xq.w, (4 * q + 3) % 12, (4 * q + 4) % 12, oq.w);
            *reinterpret_cast<f32x4*>(&lds[sl]) = oq;
        }
        CBAR();

        // 4. transpose-read outputs (24 x b128) and non-temporal store
        #pragma unroll
        for (int m = 0; m < 24; ++m) {
            const f32x4 o = *reinterpret_cast<const f32x4*>(&lds[lo[m]]);
            __builtin_nontemporal_store(o, &o4[gx[m] + k * F4C]);
        }
        CBAR();
    }

    // ---- tail: steps 480..511 (32 steps, phase 480%12 == 0) ----
    // tail x values were loaded during iteration k == NCH-1 into vx[0..7]
    {
        #pragma unroll
        for (int m = 0; m < 8; ++m) {
            const int f = tid + SW * m;
            const int rt = f >> 3, qt = f & 7;
            *reinterpret_cast<f32x4*>(&lds[rt * SROW + ((qt ^ (rt & 7)) << 2)]) = vx[m];
        }
        CBAR();
        #pragma unroll
        for (int q = 0; q < 8; ++q) {
            const int sl = tid * SROW + ((q ^ t7) << 2);
            const f32x4 xq = *reinterpret_cast<const f32x4*>(&lds[sl]);
            f32x4 oq;
            STEPM(xq.x, (4 * q + 0) % 12, (4 * q + 1) % 12, oq.x);
            STEPM(xq.y, (4 * q + 1) % 12, (4 * q + 2) % 12, oq.y);
            STEPM(xq.z, (4 * q + 2) % 12, (4 * q + 3) % 12, oq.z);
            STEPM(xq.w, (4 * q + 3) % 12, (4 * q + 4) % 12, oq.w);
            *reinterpret_cast<f32x4*>(&lds[sl]) = oq;
        }
        CBAR();
        #pragma unroll
        for (int m = 0; m < 8; ++m) {
            const int f = tid + SW * m;
            const int rt = f >> 3, qt = f & 7;
            const f32x4 o = *reinterpret_cast<const f32x4*>(
                &lds[rt * SROW + ((qt ^ (rt & 7)) << 2)]);
            __builtin_nontemporal_store(o, &o4[(size_t)rt * PITCH4 + 120 + qt]);
        }
    }
}

extern "C" void kernel_launch(void* const* d_in, const int* in_sizes, int n_in,
                              void* d_out, int out_size, void* d_ws, size_t ws_size,
                              hipStream_t stream)
{
    const float* x       = (const float*)d_in[0];
    const float* p_alpha = (const float*)d_in[1];
    const float* p_beta  = (const float*)d_in[2];
    const float* p_phi   = (const float*)d_in[3];
    const float* p_gamma = (const float*)d_in[4];
    const float* l0      = (const float*)d_in[5];
    const float* b0      = (const float*)d_in[6];
    const float* s0      = (const float*)d_in[7];
    float* out = (float*)d_out;

    const int B = in_sizes[5];          // l0 has B elements
    const int grid = B / SW;            // 1024 blocks of 64 threads

    esrnn_kernel<<<grid, SW, 0, stream>>>(x, p_alpha, p_beta, p_phi, p_gamma,
                                          l0, b0, s0, out);
}